// Round 6
// baseline (94.587 us; speedup 1.0000x reference)
//
#include <hip/hip_runtime.h>
#include <hip/hip_bf16.h>
#include <math.h>

// Problem constants (fixed by setup_inputs): b=2, n=8192, c=64, k=32
#define NPTS   8192
#define NBATCH 2
#define NQ     (NPTS * NBATCH)   // 16384 total query points
#define KNB    32                // neighbors per query
#define CFEAT  64
#define QW     4                 // queries per wave
#define NWAVES 4                 // waves per block
#define QB     (QW * NWAVES)     // 16 queries per block
#define CHUNK  2048              // staged points per LDS chunk
#define NBLK1  (NQ / QB)         // 1024 blocks for kernel 1
#define BN_EPS 1e-5f

// ws layout (in floats)
#define WS_H     0                        // h values: NQ*3*KNB = 1,572,864 floats
#define WS_PART  (NQ * 3 * KNB)           // partial sums: 6 * NBLK1 floats

// ---------------------------------------------------------------------------
// Kernel 1: ball query (first-K in index order) + h = w1*rel + BN partial sums
// One wave handles QW queries; lanes parallel over candidate j.
// SELECTION: f32 screen with conservative band (+-1e-5 around r^2); words with
// any lane inside the band (~1e-3 of words) are re-decided entirely in f64
// with the exact R4 formula. Final neighbor sets are bit-identical to R4's
// all-f64 selection, at ~half the VALU cost.
// ---------------------------------------------------------------------------
__global__ __launch_bounds__(256) void k1_ballquery(
    const float* __restrict__ pos, const float* __restrict__ w1,
    const float* __restrict__ radius, float* __restrict__ ws)
{
    __shared__ float4 spos[CHUNK];        // xyz + f32 sq, 32 KB
    __shared__ int    slist[QB][KNB];     // neighbor index lists, 2 KB
    __shared__ float  sred[NWAVES * 6];   // block reduction scratch

    const int tid  = threadIdx.x;
    const int lane = tid & 63;
    const int wave = tid >> 6;
    const int qbase = blockIdx.x * QB;          // global query base
    const int batch = qbase / NPTS;             // whole block in one batch (QB | NPTS)
    const float* bpos = pos + (size_t)batch * NPTS * 3;
    const int qloc0 = (qbase - batch * NPTS) + wave * QW;

    // Load this wave's query positions (wave-uniform)
    float  qx[QW], qy[QW], qz[QW], qsq[QW];
    double qsqd[QW];
#pragma unroll
    for (int q = 0; q < QW; ++q) {
        const float* pq = bpos + (size_t)(qloc0 + q) * 3;
        float x = pq[0], y = pq[1], z = pq[2];
        qx[q] = x; qy[q] = y; qz[q] = z;
        qsq[q] = fmaf(z, z, fmaf(y, y, x * x));          // f32 screen version
        double xd = (double)x, yd = (double)y, zd = (double)z;
        qsqd[q] = fma(zd, zd, fma(yd, yd, xd * xd));     // exact version
    }
    const double rd   = (double)radius[0];
    const double r2d  = rd * rd;
    const float  r2lo = (float)(r2d - 1e-5);             // certain-in bound
    const float  r2hi = (float)(r2d + 1e-5);             // possible-in bound

    int cnt[QW];
#pragma unroll
    for (int q = 0; q < QW; ++q) cnt[q] = 0;

    for (int cbase = 0; cbase < NPTS; cbase += CHUNK) {
        __syncthreads();
        // stage chunk: xyz + f32 sq (screen only; f64 path recomputes from xyz)
        for (int p = tid; p < CHUNK; p += 256) {
            const float* pp = bpos + (size_t)(cbase + p) * 3;
            float x = pp[0], y = pp[1], z = pp[2];
            spos[p] = make_float4(x, y, z, fmaf(z, z, fmaf(y, y, x * x)));
        }
        __syncthreads();

        bool done = (cnt[0] >= KNB) & (cnt[1] >= KNB) &
                    (cnt[2] >= KNB) & (cnt[3] >= KNB);
        for (int w = 0; w < CHUNK / 64 && !done; ++w) {
            float4 pj = spos[w * 64 + lane];
            const int j0 = cbase + w * 64;
#pragma unroll
            for (int q = 0; q < QW; ++q) {
                if (cnt[q] >= KNB) continue;               // uniform skip
                // f32 screen: d2 = (sq_i + sq_j) - 2*dot
                float dot = fmaf(pj.z, qz[q], fmaf(pj.y, qy[q], pj.x * qx[q]));
                float t   = qsq[q] + pj.w;
                float d2  = fmaf(-2.0f, dot, t);
                unsigned long long bin = __ballot(d2 < r2lo);
                unsigned long long bmb = __ballot(d2 < r2hi);
                unsigned long long bal;
                if (bmb != bin) {
                    // rare (~1e-3 of words): exact f64 decision (R4 formula)
                    double xj = (double)pj.x, yj = (double)pj.y, zj = (double)pj.z;
                    double sqj = fma(zj, zj, fma(yj, yj, xj * xj));
                    double dtd = fma(zj, (double)qz[q],
                                 fma(yj, (double)qy[q], xj * (double)qx[q]));
                    double td  = qsqd[q] + sqj;
                    double dd  = td - 2.0 * dtd;
                    bal = __ballot(dd < r2d);
                } else {
                    bal = bin;
                }
                // uniform in-order extraction (~0.5 hits per word on average)
                while (bal != 0ull && cnt[q] < KNB) {
                    int b = __ffsll((long long)bal) - 1;
                    if (lane == 0) slist[wave * QW + q][cnt[q]] = j0 + b;
                    cnt[q]++;
                    bal &= bal - 1ull;
                }
            }
            done = (cnt[0] >= KNB) & (cnt[1] >= KNB) &
                   (cnt[2] >= KNB) & (cnt[3] >= KNB);
        }
    }
    __syncthreads();   // make lane-0 slist writes visible wave/block-wide

    // Epilogue: compute h for K slots (pad with first hit), store + local stats
    float w1r[9];
#pragma unroll
    for (int i = 0; i < 9; ++i) w1r[i] = w1[i];   // w1[d][c] row-major

    float ls0 = 0.f, ls1 = 0.f, ls2 = 0.f;
    float lq0 = 0.f, lq1 = 0.f, lq2 = 0.f;

#pragma unroll
    for (int q = 0; q < QW; ++q) {
        if (lane < KNB) {
            const int qslot = wave * QW + q;
            const int kk = lane;
            // self is always a hit (d2==0.0 exactly) so cnt >= 1
            int j = slist[qslot][kk < cnt[q] ? kk : 0];
            const float* pj = bpos + (size_t)j * 3;
            float rx = __fsub_rn(pj[0], qx[q]);
            float ry = __fsub_rn(pj[1], qy[q]);
            float rz = __fsub_rn(pj[2], qz[q]);
            // h = rel . w1[d,:]  — GEMM FMA chain
            float h0 = fmaf(rz, w1r[2], fmaf(ry, w1r[1], __fmul_rn(rx, w1r[0])));
            float h1 = fmaf(rz, w1r[5], fmaf(ry, w1r[4], __fmul_rn(rx, w1r[3])));
            float h2 = fmaf(rz, w1r[8], fmaf(ry, w1r[7], __fmul_rn(rx, w1r[6])));
            const int qg = qbase + wave * QW + q;
            float* hout = ws + WS_H + (size_t)qg * 3 * KNB;
            hout[0 * KNB + kk] = h0;
            hout[1 * KNB + kk] = h1;
            hout[2 * KNB + kk] = h2;
            ls0 += h0; ls1 += h1; ls2 += h2;
            lq0 += h0 * h0; lq1 += h1 * h1; lq2 += h2 * h2;
        }
    }

    // wave-level reduction (lanes >= 32 contribute 0)
#pragma unroll
    for (int m = 1; m < 64; m <<= 1) {
        ls0 += __shfl_xor(ls0, m); ls1 += __shfl_xor(ls1, m); ls2 += __shfl_xor(ls2, m);
        lq0 += __shfl_xor(lq0, m); lq1 += __shfl_xor(lq1, m); lq2 += __shfl_xor(lq2, m);
    }
    if (lane == 0) {
        sred[wave * 6 + 0] = ls0; sred[wave * 6 + 1] = ls1; sred[wave * 6 + 2] = ls2;
        sred[wave * 6 + 3] = lq0; sred[wave * 6 + 4] = lq1; sred[wave * 6 + 5] = lq2;
    }
    __syncthreads();
    if (tid == 0) {
#pragma unroll
        for (int c = 0; c < 6; ++c) {
            float s = sred[c] + sred[6 + c] + sred[12 + c] + sred[18 + c];
            ws[WS_PART + c * NBLK1 + blockIdx.x] = s;   // deterministic partials
        }
    }
}

// ---------------------------------------------------------------------------
// Kernel 2 (fused stats + MLP): every block redundantly reduces the 6*NBLK1
// partials (24 KB, L2-hot) to mean/inv, then per wave processes QW queries:
// g = relu(((h-mean)*inv)*gamma + beta); pe = max_k(g.w2[e] + b2[e]);
// out = x + pe.  1024 blocks x 256 threads, 16 queries per block.
// ---------------------------------------------------------------------------
__global__ __launch_bounds__(256) void k3_mlp(
    const float* __restrict__ ws, const float* __restrict__ gamma,
    const float* __restrict__ beta, const float* __restrict__ w2,
    const float* __restrict__ b2, const float* __restrict__ x,
    float* __restrict__ out)
{
    __shared__ float wred[NWAVES][6];
    __shared__ float sstat[6];                 // mean[3], inv[3]
    __shared__ float g[NWAVES][KNB][3];

    const int tid  = threadIdx.x;
    const int lane = tid & 63;
    const int wave = tid >> 6;

    // ---- stats prologue (block-redundant) ----
#pragma unroll
    for (int c = 0; c < 6; ++c) {
        float s = 0.f;
        for (int i = tid; i < NBLK1; i += 256) s += ws[WS_PART + c * NBLK1 + i];
#pragma unroll
        for (int m = 1; m < 64; m <<= 1) s += __shfl_xor(s, m);
        if (lane == 0) wred[wave][c] = s;
    }
    __syncthreads();
    if (tid < 3) {
        const double N = (double)((long long)NQ * KNB);
        double s = 0.0, sq = 0.0;
#pragma unroll
        for (int w = 0; w < NWAVES; ++w) { s += wred[w][tid]; sq += wred[w][3 + tid]; }
        double mean = s / N;
        double var  = sq / N - mean * mean;
        sstat[tid]     = (float)mean;
        sstat[3 + tid] = (float)(1.0 / sqrt(var + (double)BN_EPS));
    }
    __syncthreads();

    const float m0 = sstat[0], m1 = sstat[1], m2 = sstat[2];
    const float i0 = sstat[3], i1 = sstat[4], i2 = sstat[5];
    const float g0c = gamma[0], g1c = gamma[1], g2c = gamma[2];
    const float b0c = beta[0],  b1c = beta[1],  b2c = beta[2];
    const float w20 = w2[lane * 3 + 0];
    const float w21 = w2[lane * 3 + 1];
    const float w22 = w2[lane * 3 + 2];
    const float bias = b2[lane];

    const int qg0 = blockIdx.x * QB + wave * QW;
#pragma unroll
    for (int q = 0; q < QW; ++q) {
        const int qg = qg0 + q;
        if (lane < KNB) {
            const float* hin = ws + WS_H + (size_t)qg * 3 * KNB;
            float h0 = hin[0 * KNB + lane];
            float h1 = hin[1 * KNB + lane];
            float h2 = hin[2 * KNB + lane];
            // ((h - mean) * inv) * gamma + beta, stepwise rounded
            float n0 = __fadd_rn(__fmul_rn(__fmul_rn(__fsub_rn(h0, m0), i0), g0c), b0c);
            float n1 = __fadd_rn(__fmul_rn(__fmul_rn(__fsub_rn(h1, m1), i1), g1c), b1c);
            float n2 = __fadd_rn(__fmul_rn(__fmul_rn(__fsub_rn(h2, m2), i2), g2c), b2c);
            g[wave][lane][0] = fmaxf(n0, 0.0f);
            g[wave][lane][1] = fmaxf(n1, 0.0f);
            g[wave][lane][2] = fmaxf(n2, 0.0f);
        }
        __syncthreads();   // conservative: order LDS write->read (cheap, uniform)
        float m = -INFINITY;
#pragma unroll 4
        for (int kk = 0; kk < KNB; ++kk) {
            float ga = g[wave][kk][0], gb = g[wave][kk][1], gc = g[wave][kk][2];
            float pe = __fadd_rn(fmaf(gc, w22, fmaf(gb, w21, __fmul_rn(ga, w20))), bias);
            m = fmaxf(m, pe);
        }
        const size_t o = (size_t)qg * CFEAT + lane;
        out[o] = __fadd_rn(x[o], m);
        __syncthreads();   // protect g[] before next query's overwrite
    }
}

// ---------------------------------------------------------------------------
extern "C" void kernel_launch(void* const* d_in, const int* in_sizes, int n_in,
                              void* d_out, int out_size, void* d_ws, size_t ws_size,
                              hipStream_t stream) {
    (void)in_sizes; (void)n_in; (void)out_size; (void)ws_size;
    const float* pos    = (const float*)d_in[0];
    const float* x      = (const float*)d_in[1];
    const float* w1     = (const float*)d_in[2];
    const float* gamma  = (const float*)d_in[3];
    const float* beta   = (const float*)d_in[4];
    const float* w2     = (const float*)d_in[5];
    const float* b2     = (const float*)d_in[6];
    const float* radius = (const float*)d_in[7];
    // d_in[8] = k, fixed at 32 (compile-time KNB)
    float* out = (float*)d_out;
    float* ws  = (float*)d_ws;

    hipLaunchKernelGGL(k1_ballquery, dim3(NBLK1), dim3(256), 0, stream,
                       pos, w1, radius, ws);
    hipLaunchKernelGGL(k3_mlp, dim3(NBLK1), dim3(256), 0, stream,
                       ws, gamma, beta, w2, b2, x, out);
}

// Round 8
// 85.002 us; speedup vs baseline: 1.1128x; 1.1128x over previous
//
#include <hip/hip_runtime.h>
#include <hip/hip_bf16.h>
#include <math.h>

// Problem constants (fixed by setup_inputs): b=2, n=8192, c=64, k=32
#define NPTS   8192
#define NBATCH 2
#define NQ     (NPTS * NBATCH)   // 16384 total query points
#define KNB    32                // neighbors per query
#define CFEAT  64
#define BN_EPS 1e-5f

// k1 geometry: 2 query-groups x 4 queries, 2 candidate slices -> 4 waves/block
#define QW     4                 // queries per group (per wave)
#define NGRP   2                 // query groups per block
#define NSLC   2                 // candidate slices per query
#define QB     (QW * NGRP)       // 8 queries per block
#define NBLK1  (NQ / QB)         // 2048 blocks
#define HALF   (NPTS / NSLC)     // 4096 candidates per slice
#define CHUNK  512               // staged points per slice-chunk
#define NCH    (HALF / CHUNK)    // 8 chunk iterations
#define WPC    (CHUNK / 64)      // 8 words per chunk

// k3 geometry
#define QB3    16
#define NBLK3  (NQ / QB3)        // 1024 blocks

// ws layout (in floats)
#define WS_H     0                        // h values: NQ*3*KNB floats
#define WS_PART  (NQ * 3 * KNB)           // partial sums: 6 * NBLK1 floats

// ---------------------------------------------------------------------------
// Kernel 1: ball query (first-K in index order) + h = w1*rel + BN partials.
// Wave (grp,slc) scans slice slc of the candidates for the QW queries of
// group grp. Screen: f32 d2 vs conservative band [r2-1e-5, r2+1e-5]; words
// touching the band (rare) are re-decided in f64 (bit-identical to R4).
// Hits extracted in parallel via mbcnt rank (no serial while loop).
// Slice hit-lists are merged in index order in the epilogue.
// ---------------------------------------------------------------------------
__global__ __launch_bounds__(256) void k1_ballquery(
    const float* __restrict__ pos, const float* __restrict__ w1,
    const float* __restrict__ radius, float* __restrict__ ws)
{
    __shared__ float4 spos[NSLC][CHUNK];            // (-2x,-2y,-2z, sq) 16 KB
    __shared__ int    slist[NGRP][QW][NSLC][KNB];   // 2 KB
    __shared__ int    scnt[NGRP][QW][NSLC];
    __shared__ float  sred[4][6];

    const int tid  = threadIdx.x;
    const int lane = tid & 63;
    const int wave = tid >> 6;
    const int grp  = wave >> 1;
    const int slc  = wave & 1;
    const int qbase = blockIdx.x * QB;          // global query base
    const int batch = qbase / NPTS;             // QB | NPTS so block in one batch
    const float* bpos = pos + (size_t)batch * NPTS * 3;
    const int qloc0 = (qbase - batch * NPTS) + grp * QW;

    // Query state (f32 only; f64 derived on demand in the rare path)
    float qx[QW], qy[QW], qz[QW], qsq[QW];
#pragma unroll
    for (int q = 0; q < QW; ++q) {
        const float* pq = bpos + (size_t)(qloc0 + q) * 3;
        float x = pq[0], y = pq[1], z = pq[2];
        qx[q] = x; qy[q] = y; qz[q] = z;
        qsq[q] = fmaf(z, z, fmaf(y, y, x * x));   // screen-only value
    }
    const double rd   = (double)radius[0];
    const double r2d  = rd * rd;
    const float  r2lo = (float)(r2d - 1e-5);
    const float  r2hi = (float)(r2d + 1e-5);

    int cnt[QW];
#pragma unroll
    for (int q = 0; q < QW; ++q) cnt[q] = 0;

    for (int ch = 0; ch < NCH; ++ch) {
        __syncthreads();
        // stage one chunk per slice: (-2x,-2y,-2z, sq)
        for (int p = tid; p < NSLC * CHUNK; p += 256) {
            const int s   = p >> 9;              // CHUNK == 512
            const int off = p & (CHUNK - 1);
            const float* pp = bpos + (size_t)(s * HALF + ch * CHUNK + off) * 3;
            float x = pp[0], y = pp[1], z = pp[2];
            spos[s][off] = make_float4(-2.0f * x, -2.0f * y, -2.0f * z,
                                       fmaf(z, z, fmaf(y, y, x * x)));
        }
        __syncthreads();

        const int base = slc * HALF + ch * CHUNK;
        float4 nxt = spos[slc][lane];
        for (int w = 0; w < WPC; ++w) {
            const float4 cur = nxt;
            if (w + 1 < WPC) nxt = spos[slc][(w + 1) * 64 + lane];
            const int j0 = base + w * 64;
#pragma unroll
            for (int q = 0; q < QW; ++q) {
                // screen d2 = sq_i + (sq_j - 2*dot), 4 VALU
                float d2 = qsq[q] + fmaf(cur.x, qx[q],
                                    fmaf(cur.y, qy[q],
                                    fmaf(cur.z, qz[q], cur.w)));
                bool hi = d2 < r2hi;
                unsigned long long bhi = __ballot(hi);
                if (bhi != 0ull && cnt[q] < KNB) {     // ~24% of query-words
                    bool lo = d2 < r2lo;
                    unsigned long long blo = __ballot(lo);
                    unsigned long long bal; bool in;
                    if (bhi != blo) {
                        // rare: exact f64 decision, bit-identical to R4
                        double xj = (double)cur.x * -0.5;
                        double yj = (double)cur.y * -0.5;
                        double zj = (double)cur.z * -0.5;
                        double sqj = fma(zj, zj, fma(yj, yj, xj * xj));
                        double qxd = (double)qx[q], qyd = (double)qy[q], qzd = (double)qz[q];
                        double qsd = fma(qzd, qzd, fma(qyd, qyd, qxd * qxd));
                        double dot = fma(zj, qzd, fma(yj, qyd, xj * qxd));
                        double dd  = (qsd + sqj) - 2.0 * dot;
                        in  = dd < r2d;
                        bal = __ballot(in);
                    } else { in = lo; bal = blo; }
                    if (in) {
                        unsigned rank = __builtin_amdgcn_mbcnt_hi(
                            (unsigned)(bal >> 32),
                            __builtin_amdgcn_mbcnt_lo((unsigned)bal, 0u));
                        int slot = cnt[q] + (int)rank;
                        if (slot < KNB) slist[grp][q][slc][slot] = j0 + lane;
                    }
                    cnt[q] += (int)__popcll(bal);
                }
            }
        }
    }
    if (lane == 0) {
#pragma unroll
        for (int q = 0; q < QW; ++q) scnt[grp][q][slc] = cnt[q];
    }
    __syncthreads();

    // ---- merge slices + h epilogue + BN partials: 2 queries per wave ----
    float w1r[9];
#pragma unroll
    for (int i = 0; i < 9; ++i) w1r[i] = w1[i];

    float ls0 = 0.f, ls1 = 0.f, ls2 = 0.f;
    float lq0 = 0.f, lq1 = 0.f, lq2 = 0.f;

#pragma unroll
    for (int e = 0; e < 2; ++e) {
        const int qe = wave * 2 + e;          // 0..7
        const int ge = qe >> 2, qq = qe & 3;
        const int qg = qbase + qe;
        const float* pq = bpos + (size_t)(qg - batch * NPTS) * 3;
        const float qxx = pq[0], qyy = pq[1], qzz = pq[2];
        int cA = scnt[ge][qq][0]; cA = cA < KNB ? cA : KNB;
        const int cB = scnt[ge][qq][1];
        if (lane < KNB) {
            const int jA0 = slist[ge][qq][0][0];
            const int jB0 = slist[ge][qq][1][0];
            const int first = (cA > 0) ? jA0 : jB0;   // first in-order hit
            int j;
            if (lane < cA) j = slist[ge][qq][0][lane];
            else {
                const int t = lane - cA;
                j = (t < cB) ? slist[ge][qq][1][t] : first;
            }
            const float* pj = bpos + (size_t)j * 3;
            float rx = __fsub_rn(pj[0], qxx);
            float ry = __fsub_rn(pj[1], qyy);
            float rz = __fsub_rn(pj[2], qzz);
            float h0 = fmaf(rz, w1r[2], fmaf(ry, w1r[1], __fmul_rn(rx, w1r[0])));
            float h1 = fmaf(rz, w1r[5], fmaf(ry, w1r[4], __fmul_rn(rx, w1r[3])));
            float h2 = fmaf(rz, w1r[8], fmaf(ry, w1r[7], __fmul_rn(rx, w1r[6])));
            float* hout = ws + WS_H + (size_t)qg * 3 * KNB;
            hout[0 * KNB + lane] = h0;
            hout[1 * KNB + lane] = h1;
            hout[2 * KNB + lane] = h2;
            ls0 += h0; ls1 += h1; ls2 += h2;
            lq0 += h0 * h0; lq1 += h1 * h1; lq2 += h2 * h2;
        }
    }

    // wave reduce (lanes >= 32 contribute 0) then block reduce
#pragma unroll
    for (int m = 1; m < 64; m <<= 1) {
        ls0 += __shfl_xor(ls0, m); ls1 += __shfl_xor(ls1, m); ls2 += __shfl_xor(ls2, m);
        lq0 += __shfl_xor(lq0, m); lq1 += __shfl_xor(lq1, m); lq2 += __shfl_xor(lq2, m);
    }
    if (lane == 0) {
        sred[wave][0] = ls0; sred[wave][1] = ls1; sred[wave][2] = ls2;
        sred[wave][3] = lq0; sred[wave][4] = lq1; sred[wave][5] = lq2;
    }
    __syncthreads();
    if (tid == 0) {
#pragma unroll
        for (int c = 0; c < 6; ++c) {
            float s = sred[0][c] + sred[1][c] + sred[2][c] + sred[3][c];
            ws[WS_PART + c * NBLK1 + blockIdx.x] = s;
        }
    }
}

// ---------------------------------------------------------------------------
// Kernel 3 (fused stats + MLP): every block redundantly reduces the 6*NBLK1
// partials (48 KB, L2-hot) to mean/inv, then per wave processes 4 queries:
// g = relu(((h-mean)*inv)*gamma + beta); pe = max_k(g.w2[e] + b2[e]);
// out = x + pe.
// ---------------------------------------------------------------------------
__global__ __launch_bounds__(256) void k3_mlp(
    const float* __restrict__ ws, const float* __restrict__ gamma,
    const float* __restrict__ beta, const float* __restrict__ w2,
    const float* __restrict__ b2, const float* __restrict__ x,
    float* __restrict__ out)
{
    __shared__ float wred[4][6];
    __shared__ float sstat[6];                 // mean[3], inv[3]
    __shared__ float g[4][KNB][3];

    const int tid  = threadIdx.x;
    const int lane = tid & 63;
    const int wave = tid >> 6;

    // ---- stats prologue (block-redundant) ----
#pragma unroll
    for (int c = 0; c < 6; ++c) {
        float s = 0.f;
        for (int i = tid; i < NBLK1; i += 256) s += ws[WS_PART + c * NBLK1 + i];
#pragma unroll
        for (int m = 1; m < 64; m <<= 1) s += __shfl_xor(s, m);
        if (lane == 0) wred[wave][c] = s;
    }
    __syncthreads();
    if (tid < 3) {
        const double N = (double)((long long)NQ * KNB);
        double s = 0.0, sq = 0.0;
#pragma unroll
        for (int w = 0; w < 4; ++w) { s += wred[w][tid]; sq += wred[w][3 + tid]; }
        double mean = s / N;
        double var  = sq / N - mean * mean;
        sstat[tid]     = (float)mean;
        sstat[3 + tid] = (float)(1.0 / sqrt(var + (double)BN_EPS));
    }
    __syncthreads();

    const float m0 = sstat[0], m1 = sstat[1], m2 = sstat[2];
    const float i0 = sstat[3], i1 = sstat[4], i2 = sstat[5];
    const float g0c = gamma[0], g1c = gamma[1], g2c = gamma[2];
    const float b0c = beta[0],  b1c = beta[1],  b2c = beta[2];
    const float w20 = w2[lane * 3 + 0];
    const float w21 = w2[lane * 3 + 1];
    const float w22 = w2[lane * 3 + 2];
    const float bias = b2[lane];

    const int qg0 = blockIdx.x * QB3 + wave * 4;
#pragma unroll
    for (int q = 0; q < 4; ++q) {
        const int qg = qg0 + q;
        if (lane < KNB) {
            const float* hin = ws + WS_H + (size_t)qg * 3 * KNB;
            float h0 = hin[0 * KNB + lane];
            float h1 = hin[1 * KNB + lane];
            float h2 = hin[2 * KNB + lane];
            // ((h - mean) * inv) * gamma + beta, stepwise rounded
            float n0 = __fadd_rn(__fmul_rn(__fmul_rn(__fsub_rn(h0, m0), i0), g0c), b0c);
            float n1 = __fadd_rn(__fmul_rn(__fmul_rn(__fsub_rn(h1, m1), i1), g1c), b1c);
            float n2 = __fadd_rn(__fmul_rn(__fmul_rn(__fsub_rn(h2, m2), i2), g2c), b2c);
            g[wave][lane][0] = fmaxf(n0, 0.0f);
            g[wave][lane][1] = fmaxf(n1, 0.0f);
            g[wave][lane][2] = fmaxf(n2, 0.0f);
        }
        __syncthreads();
        float m = -INFINITY;
#pragma unroll 4
        for (int kk = 0; kk < KNB; ++kk) {
            float ga = g[wave][kk][0], gb = g[wave][kk][1], gc = g[wave][kk][2];
            float pe = __fadd_rn(fmaf(gc, w22, fmaf(gb, w21, __fmul_rn(ga, w20))), bias);
            m = fmaxf(m, pe);
        }
        const size_t o = (size_t)qg * CFEAT + lane;
        out[o] = __fadd_rn(x[o], m);
        __syncthreads();
    }
}

// ---------------------------------------------------------------------------
extern "C" void kernel_launch(void* const* d_in, const int* in_sizes, int n_in,
                              void* d_out, int out_size, void* d_ws, size_t ws_size,
                              hipStream_t stream) {
    (void)in_sizes; (void)n_in; (void)out_size; (void)ws_size;
    const float* pos    = (const float*)d_in[0];
    const float* x      = (const float*)d_in[1];
    const float* w1     = (const float*)d_in[2];
    const float* gamma  = (const float*)d_in[3];
    const float* beta   = (const float*)d_in[4];
    const float* w2     = (const float*)d_in[5];
    const float* b2     = (const float*)d_in[6];
    const float* radius = (const float*)d_in[7];
    // d_in[8] = k, fixed at 32 (compile-time KNB)
    float* out = (float*)d_out;
    float* ws  = (float*)d_ws;

    hipLaunchKernelGGL(k1_ballquery, dim3(NBLK1), dim3(256), 0, stream,
                       pos, w1, radius, ws);
    hipLaunchKernelGGL(k3_mlp, dim3(NBLK3), dim3(256), 0, stream,
                       ws, gamma, beta, w2, b2, x, out);
}

// Round 9
// 69.674 us; speedup vs baseline: 1.3576x; 1.2200x over previous
//
#include <hip/hip_runtime.h>
#include <math.h>

// Problem constants (fixed by setup_inputs): b=2, n=8192, c=64, k=32
#define NPTS   8192
#define NBATCH 2
#define NQ     (NPTS * NBATCH)
#define KNB    32
#define CFEAT  64
#define BN_EPS 1e-5f

#define MAXC     1000          // max cells (G capped at 10)
#define CSTR     1024          // cellstart stride per batch (ints)
#define CAP_HIT  128           // max hits kept per query (P(exceed) ~ 1e-25)
#define CAP_CAND 640           // max candidates in 27 cells (27*avg11 ~ 300)

#define QBK2  16               // queries per block in k2 (4 waves x 4)
#define NBLK2 (NQ / QBK2)      // 1024

// ws layout (floats)
#define WS_H    0                          // h values: NQ*3*KNB
#define WS_PART (NQ * 3 * KNB)             // 6 * NBLK2 partial sums
#define WS_CS   (WS_PART + 6 * NBLK2)      // cellstart: 2 * CSTR ints
#define WS_BIN  (WS_CS + 2 * CSTR)         // binned float4: 2*NPTS*4 floats

__device__ __forceinline__ int grid_from_r(double rd) {
    int G = (int)(1.0 / rd);
    if (G < 1) G = 1;
    while (G > 1 && 1.0 / (double)G < rd) --G;   // ensure cellsize >= r
    if (G > 10) G = 10;                          // static-array cap (coverage still exact)
    return G;
}

__device__ __forceinline__ int mbcnt64(unsigned long long m) {
    return (int)__builtin_amdgcn_mbcnt_hi((unsigned)(m >> 32),
             __builtin_amdgcn_mbcnt_lo((unsigned)m, 0u));
}

// ---------------------------------------------------------------------------
// kA: bin points into a GxGxG grid (one block per batch).
// hist -> block exclusive scan -> scatter (unstable order; only the SET of
// cell members matters downstream). binned[slot] = (x,y,z, idx-as-float).
// ---------------------------------------------------------------------------
__global__ __launch_bounds__(256) void kA_bin(
    const float* __restrict__ pos, const float* __restrict__ radius,
    float* __restrict__ ws)
{
    __shared__ int hist[MAXC];
    __shared__ int offs[MAXC + 1];
    __shared__ int cur[MAXC];
    __shared__ int scan[256];

    const int tid = threadIdx.x;
    const int batch = blockIdx.x;
    const float* bpos = pos + (size_t)batch * NPTS * 3;
    const double rd = (double)radius[0];
    const int G = grid_from_r(rd);
    const float Gf = (float)G;
    const int NC = G * G * G;

    for (int c = tid; c < NC; c += 256) hist[c] = 0;
    __syncthreads();
    for (int p = tid; p < NPTS; p += 256) {
        float x = bpos[p * 3], y = bpos[p * 3 + 1], z = bpos[p * 3 + 2];
        int cx = min((int)(x * Gf), G - 1);
        int cy = min((int)(y * Gf), G - 1);
        int cz = min((int)(z * Gf), G - 1);
        atomicAdd(&hist[(cz * G + cy) * G + cx], 1);
    }
    __syncthreads();

    // exclusive scan over NC cells, CH cells/thread + Hillis-Steele on 256
    const int CH = (MAXC + 255) / 256;   // 4
    const int base = tid * CH;
    int s = 0;
#pragma unroll
    for (int i = 0; i < CH; ++i) { int c = base + i; s += (c < NC) ? hist[c] : 0; }
    scan[tid] = s;
    __syncthreads();
    for (int off = 1; off < 256; off <<= 1) {
        int v = (tid >= off) ? scan[tid - off] : 0;
        __syncthreads();
        scan[tid] += v;
        __syncthreads();
    }
    int excl = (tid > 0) ? scan[tid - 1] : 0;
#pragma unroll
    for (int i = 0; i < CH; ++i) {
        int c = base + i;
        if (c < NC) { offs[c] = excl; excl += hist[c]; }
    }
    if (tid == 0) offs[NC] = NPTS;
    __syncthreads();
    for (int c = tid; c < NC; c += 256) cur[c] = offs[c];
    int* cs = (int*)ws + WS_CS + batch * CSTR;
    for (int c = tid; c <= NC; c += 256) cs[c] = offs[c];
    __syncthreads();

    float4* bin = (float4*)(ws + WS_BIN) + (size_t)batch * NPTS;
    for (int p = tid; p < NPTS; p += 256) {
        float x = bpos[p * 3], y = bpos[p * 3 + 1], z = bpos[p * 3 + 2];
        int cx = min((int)(x * Gf), G - 1);
        int cy = min((int)(y * Gf), G - 1);
        int cz = min((int)(z * Gf), G - 1);
        int slot = atomicAdd(&cur[(cz * G + cy) * G + cx], 1);
        bin[slot] = make_float4(x, y, z, __int_as_float(p));
    }
}

// ---------------------------------------------------------------------------
// k2: per query, scan the 27 neighbor cells (~300 candidates), f64 distance
// (R4's exact formula -> selection set bit-identical to the passing R4/R8),
// keep the 32 smallest hit indices (binary-search kth when cnt>32), compute
// h = w1*rel per slot, store h + BN partial sums.
// One wave per 4 queries; all LDS wave-private (no block barriers in loop).
// ---------------------------------------------------------------------------
__global__ __launch_bounds__(256) void k2_query(
    const float* __restrict__ pos, const float* __restrict__ w1,
    const float* __restrict__ radius, float* __restrict__ ws)
{
    __shared__ int   candl[4][CAP_CAND];     // 10 KB
    __shared__ int   hitl[QBK2][CAP_HIT];    // 8 KB
    __shared__ int   seli[4][KNB];           // 512 B
    __shared__ float sred[4][6];

    const int tid = threadIdx.x, lane = tid & 63, wave = tid >> 6;
    const int qbase = blockIdx.x * QBK2;
    const int batch = qbase / NPTS;          // QBK2 | NPTS
    const float* bpos = pos + (size_t)batch * NPTS * 3;
    const double rd  = (double)radius[0];
    const double r2d = rd * rd;
    const int G = grid_from_r(rd);
    const float Gf = (float)G;
    const int* cs = (const int*)ws + WS_CS + batch * CSTR;
    const float4* bin = (const float4*)(ws + WS_BIN) + (size_t)batch * NPTS;

    float w1r[9];
#pragma unroll
    for (int i = 0; i < 9; ++i) w1r[i] = w1[i];

    float ls0 = 0.f, ls1 = 0.f, ls2 = 0.f;
    float lq0 = 0.f, lq1 = 0.f, lq2 = 0.f;

    for (int q = 0; q < 4; ++q) {
        const int qg = qbase + wave * 4 + q;
        const int ql = qg - batch * NPTS;
        const float qx = bpos[ql * 3], qy = bpos[ql * 3 + 1], qz = bpos[ql * 3 + 2];
        const double qxd = (double)qx, qyd = (double)qy, qzd = (double)qz;
        const double qsd = fma(qzd, qzd, fma(qyd, qyd, qxd * qxd));
        const int cx = min((int)(qx * Gf), G - 1);
        const int cy = min((int)(qy * Gf), G - 1);
        const int cz = min((int)(qz * Gf), G - 1);

        // lanes 0..26: one neighbor cell each
        int cnt_l = 0, start_l = 0;
        if (lane < 27) {
            int dx = lane % 3 - 1, dy = (lane / 3) % 3 - 1, dz = lane / 9 - 1;
            int nx = cx + dx, ny = cy + dy, nz = cz + dz;
            if (nx >= 0 && nx < G && ny >= 0 && ny < G && nz >= 0 && nz < G) {
                int c = (nz * G + ny) * G + nx;
                start_l = cs[c];
                cnt_l = cs[c + 1] - start_l;
            }
        }
        // wave inclusive scan of counts
        int incl = cnt_l;
#pragma unroll
        for (int off = 1; off < 32; off <<= 1) {
            int v = __shfl_up(incl, off);
            if (lane >= off) incl += v;
        }
        int T = __shfl(incl, 26);
        if (T > CAP_CAND) T = CAP_CAND;
        const int pref = incl - cnt_l;
        // build candidate slot list (wave-private; DS per-wave in-order + alias)
        if (lane < 27) {
            for (int t = 0; t < cnt_l; ++t) {
                int d = pref + t;
                if (d < CAP_CAND) candl[wave][d] = start_l + t;
            }
        }

        const int qs = wave * 4 + q;
        int hc = 0;
        for (int b0 = 0; b0 < T; b0 += 64) {
            int ss = b0 + lane;
            bool act = ss < T;
            int slot = act ? candl[wave][ss] : 0;
            float4 P = bin[slot];
            double xj = (double)P.x, yj = (double)P.y, zj = (double)P.z;
            double sqj = fma(zj, zj, fma(yj, yj, xj * xj));
            double dot = fma(zj, qzd, fma(yj, qyd, xj * qxd));
            double dd  = (qsd + sqj) - 2.0 * dot;       // exact R4 formula
            bool in = act && (dd < r2d);
            unsigned long long bal = __ballot(in);
            if (in) {
                int p2 = hc + mbcnt64(bal);
                if (p2 < CAP_HIT) hitl[qs][p2] = __float_as_int(P.w);
            }
            hc += (int)__popcll(bal);
        }
        if (hc > CAP_HIT) hc = CAP_HIT;

        // ---- select the 32 smallest hit indices (set only, no order) ----
        if (hc <= KNB) {
            int v = (lane < hc) ? hitl[qs][lane] : 0x7FFFFFFF;
            int mn = v;
#pragma unroll
            for (int off = 32; off; off >>= 1) mn = min(mn, __shfl_xor(mn, off));
            if (lane < KNB) seli[wave][lane] = (lane < hc) ? v : mn;  // pad = min idx
        } else {
            int a = (lane < hc) ? hitl[qs][lane] : 0x7FFFFFFF;
            int b = (64 + lane < hc) ? hitl[qs][64 + lane] : 0x7FFFFFFF;
            int lo = 0, hi = NPTS - 1;       // find 32nd smallest (indices distinct)
            while (lo < hi) {
                int mid = (lo + hi) >> 1;
                int c1 = (int)__popcll(__ballot(a <= mid)) +
                         (int)__popcll(__ballot(b <= mid));
                if (c1 >= KNB) hi = mid; else lo = mid + 1;
            }
            const int t = lo;
            unsigned long long ba = __ballot(a <= t);
            unsigned long long bb = __ballot(b <= t);
            int na = (int)__popcll(ba);
            if (a <= t) seli[wave][mbcnt64(ba)] = a;
            if (b <= t) seli[wave][na + mbcnt64(bb)] = b;
        }

        // ---- h epilogue for this query's 32 slots ----
        if (lane < KNB) {
            int j = seli[wave][lane];
            const float* pj = bpos + (size_t)j * 3;
            float rx = __fsub_rn(pj[0], qx);
            float ry = __fsub_rn(pj[1], qy);
            float rz = __fsub_rn(pj[2], qz);
            float h0 = fmaf(rz, w1r[2], fmaf(ry, w1r[1], __fmul_rn(rx, w1r[0])));
            float h1 = fmaf(rz, w1r[5], fmaf(ry, w1r[4], __fmul_rn(rx, w1r[3])));
            float h2 = fmaf(rz, w1r[8], fmaf(ry, w1r[7], __fmul_rn(rx, w1r[6])));
            float* hout = ws + WS_H + (size_t)qg * 3 * KNB;
            hout[0 * KNB + lane] = h0;
            hout[1 * KNB + lane] = h1;
            hout[2 * KNB + lane] = h2;
            ls0 += h0; ls1 += h1; ls2 += h2;
            lq0 += h0 * h0; lq1 += h1 * h1; lq2 += h2 * h2;
        }
    }

    // wave reduce then block reduce of BN partials
#pragma unroll
    for (int m = 1; m < 64; m <<= 1) {
        ls0 += __shfl_xor(ls0, m); ls1 += __shfl_xor(ls1, m); ls2 += __shfl_xor(ls2, m);
        lq0 += __shfl_xor(lq0, m); lq1 += __shfl_xor(lq1, m); lq2 += __shfl_xor(lq2, m);
    }
    if (lane == 0) {
        sred[wave][0] = ls0; sred[wave][1] = ls1; sred[wave][2] = ls2;
        sred[wave][3] = lq0; sred[wave][4] = lq1; sred[wave][5] = lq2;
    }
    __syncthreads();
    if (tid == 0) {
#pragma unroll
        for (int c = 0; c < 6; ++c) {
            float s = sred[0][c] + sred[1][c] + sred[2][c] + sred[3][c];
            ws[WS_PART + c * NBLK2 + blockIdx.x] = s;
        }
    }
}

// ---------------------------------------------------------------------------
// k3 (fused stats + MLP): block-redundant reduction of 6*NBLK2 partials ->
// mean/inv; then g = relu(((h-mean)*inv)*gamma + beta);
// pe = max_k(g.w2[e] + b2[e]); out = x + pe.
// ---------------------------------------------------------------------------
__global__ __launch_bounds__(256) void k3_mlp(
    const float* __restrict__ ws, const float* __restrict__ gamma,
    const float* __restrict__ beta, const float* __restrict__ w2,
    const float* __restrict__ b2, const float* __restrict__ x,
    float* __restrict__ out)
{
    __shared__ float wred[4][6];
    __shared__ float sstat[6];
    __shared__ float g[4][KNB][3];

    const int tid = threadIdx.x, lane = tid & 63, wave = tid >> 6;

#pragma unroll
    for (int c = 0; c < 6; ++c) {
        float s = 0.f;
        for (int i = tid; i < NBLK2; i += 256) s += ws[WS_PART + c * NBLK2 + i];
#pragma unroll
        for (int m = 1; m < 64; m <<= 1) s += __shfl_xor(s, m);
        if (lane == 0) wred[wave][c] = s;
    }
    __syncthreads();
    if (tid < 3) {
        const double N = (double)((long long)NQ * KNB);
        double s = 0.0, sq = 0.0;
#pragma unroll
        for (int w = 0; w < 4; ++w) { s += wred[w][tid]; sq += wred[w][3 + tid]; }
        double mean = s / N;
        double var  = sq / N - mean * mean;
        sstat[tid]     = (float)mean;
        sstat[3 + tid] = (float)(1.0 / sqrt(var + (double)BN_EPS));
    }
    __syncthreads();

    const float m0 = sstat[0], m1 = sstat[1], m2 = sstat[2];
    const float i0 = sstat[3], i1 = sstat[4], i2 = sstat[5];
    const float g0c = gamma[0], g1c = gamma[1], g2c = gamma[2];
    const float b0c = beta[0],  b1c = beta[1],  b2c = beta[2];
    const float w20 = w2[lane * 3 + 0];
    const float w21 = w2[lane * 3 + 1];
    const float w22 = w2[lane * 3 + 2];
    const float bias = b2[lane];

    const int qg0 = blockIdx.x * QBK2 + wave * 4;
#pragma unroll
    for (int q = 0; q < 4; ++q) {
        const int qg = qg0 + q;
        if (lane < KNB) {
            const float* hin = ws + WS_H + (size_t)qg * 3 * KNB;
            float h0 = hin[0 * KNB + lane];
            float h1 = hin[1 * KNB + lane];
            float h2 = hin[2 * KNB + lane];
            float n0 = __fadd_rn(__fmul_rn(__fmul_rn(__fsub_rn(h0, m0), i0), g0c), b0c);
            float n1 = __fadd_rn(__fmul_rn(__fmul_rn(__fsub_rn(h1, m1), i1), g1c), b1c);
            float n2 = __fadd_rn(__fmul_rn(__fmul_rn(__fsub_rn(h2, m2), i2), g2c), b2c);
            g[wave][lane][0] = fmaxf(n0, 0.0f);
            g[wave][lane][1] = fmaxf(n1, 0.0f);
            g[wave][lane][2] = fmaxf(n2, 0.0f);
        }
        __syncthreads();
        float m = -INFINITY;
#pragma unroll 4
        for (int kk = 0; kk < KNB; ++kk) {
            float ga = g[wave][kk][0], gb = g[wave][kk][1], gc = g[wave][kk][2];
            float pe = __fadd_rn(fmaf(gc, w22, fmaf(gb, w21, __fmul_rn(ga, w20))), bias);
            m = fmaxf(m, pe);
        }
        const size_t o = (size_t)qg * CFEAT + lane;
        out[o] = __fadd_rn(x[o], m);
        __syncthreads();
    }
}

// ---------------------------------------------------------------------------
extern "C" void kernel_launch(void* const* d_in, const int* in_sizes, int n_in,
                              void* d_out, int out_size, void* d_ws, size_t ws_size,
                              hipStream_t stream) {
    (void)in_sizes; (void)n_in; (void)out_size; (void)ws_size;
    const float* pos    = (const float*)d_in[0];
    const float* x      = (const float*)d_in[1];
    const float* w1     = (const float*)d_in[2];
    const float* gamma  = (const float*)d_in[3];
    const float* beta   = (const float*)d_in[4];
    const float* w2     = (const float*)d_in[5];
    const float* b2     = (const float*)d_in[6];
    const float* radius = (const float*)d_in[7];
    // d_in[8] = k, fixed at 32 (compile-time KNB)
    float* out = (float*)d_out;
    float* ws  = (float*)d_ws;

    hipLaunchKernelGGL(kA_bin,   dim3(NBATCH), dim3(256), 0, stream, pos, radius, ws);
    hipLaunchKernelGGL(k2_query, dim3(NBLK2),  dim3(256), 0, stream, pos, w1, radius, ws);
    hipLaunchKernelGGL(k3_mlp,   dim3(NBLK2),  dim3(256), 0, stream,
                       ws, gamma, beta, w2, b2, x, out);
}

// Round 10
// 63.396 us; speedup vs baseline: 1.4920x; 1.0990x over previous
//
#include <hip/hip_runtime.h>
#include <math.h>

// Problem constants (fixed by setup_inputs): b=2, n=8192, c=64, k=32
#define NPTS   8192
#define NBATCH 2
#define NQ     (NPTS * NBATCH)
#define KNB    32
#define CFEAT  64
#define BN_EPS 1e-5f

#define MAXC     1000          // max cells (G capped at 10)
#define CSTR     1024          // cellstart stride per batch (ints)
#define CAP_HIT  128           // max hits kept per query (P(exceed) ~ 1e-40)

#define QBK2  16               // queries per block in k2 (16 waves x 1)
#define NBLK2 (NQ / QBK2)      // 1024

// ws layout (floats)
#define WS_H    0                          // h values: NQ*3*KNB
#define WS_PART (NQ * 3 * KNB)             // 6 * NBLK2 partial sums
#define WS_CS   (WS_PART + 6 * NBLK2)      // cellstart: 2 * CSTR ints
#define WS_BIN  (WS_CS + 2 * CSTR)         // binned float4: 2*NPTS*4 floats

__device__ __forceinline__ int grid_from_r(double rd) {
    int G = (int)(1.0 / rd);
    if (G < 1) G = 1;
    while (G > 1 && 1.0 / (double)G < rd) --G;   // ensure cellsize >= r
    if (G > 10) G = 10;                          // cap (coverage still exact)
    return G;
}

__device__ __forceinline__ int mbcnt64(unsigned long long m) {
    return (int)__builtin_amdgcn_mbcnt_hi((unsigned)(m >> 32),
             __builtin_amdgcn_mbcnt_lo((unsigned)m, 0u));
}

// ---------------------------------------------------------------------------
// kA: bin points into a GxGxG grid (one 1024-thread block per batch).
// hist -> exclusive scan (one cell per thread) -> scatter (unstable order;
// only the SET of cell members matters downstream).
// binned[slot] = (x,y,z, idx-as-float).
// ---------------------------------------------------------------------------
__global__ __launch_bounds__(1024) void kA_bin(
    const float* __restrict__ pos, const float* __restrict__ radius,
    float* __restrict__ ws)
{
    __shared__ int hist[MAXC];
    __shared__ int offs[MAXC + 1];
    __shared__ int cur[MAXC];
    __shared__ int scan[1024];

    const int tid = threadIdx.x;
    const int batch = blockIdx.x;
    const float* bpos = pos + (size_t)batch * NPTS * 3;
    const double rd = (double)radius[0];
    const int G = grid_from_r(rd);
    const float Gf = (float)G;
    const int NC = G * G * G;

    for (int c = tid; c < NC; c += 1024) hist[c] = 0;
    __syncthreads();
    for (int p = tid; p < NPTS; p += 1024) {
        float x = bpos[p * 3], y = bpos[p * 3 + 1], z = bpos[p * 3 + 2];
        int cx = min((int)(x * Gf), G - 1);
        int cy = min((int)(y * Gf), G - 1);
        int cz = min((int)(z * Gf), G - 1);
        atomicAdd(&hist[(cz * G + cy) * G + cx], 1);
    }
    __syncthreads();

    // inclusive scan, one cell per thread (NC <= 1000 < 1024)
    int v = (tid < NC) ? hist[tid] : 0;
    scan[tid] = v;
    __syncthreads();
    for (int off = 1; off < 1024; off <<= 1) {
        int t = (tid >= off) ? scan[tid - off] : 0;
        __syncthreads();
        scan[tid] += t;
        __syncthreads();
    }
    if (tid < NC) {
        int excl = (tid > 0) ? scan[tid - 1] : 0;
        offs[tid] = excl;
        cur[tid]  = excl;
    }
    if (tid == 0) offs[NC] = NPTS;
    __syncthreads();
    int* cs = (int*)ws + WS_CS + batch * CSTR;
    for (int c = tid; c <= NC; c += 1024) cs[c] = offs[c];

    float4* bin = (float4*)(ws + WS_BIN) + (size_t)batch * NPTS;
    for (int p = tid; p < NPTS; p += 1024) {
        float x = bpos[p * 3], y = bpos[p * 3 + 1], z = bpos[p * 3 + 2];
        int cx = min((int)(x * Gf), G - 1);
        int cy = min((int)(y * Gf), G - 1);
        int cz = min((int)(z * Gf), G - 1);
        int slot = atomicAdd(&cur[(cz * G + cy) * G + cx], 1);
        bin[slot] = make_float4(x, y, z, __int_as_float(p));
    }
}

// ---------------------------------------------------------------------------
// k2: one wave per query. The 27 neighbor cells are 9 CONTIGUOUS slot ranges
// (x is innermost in the cell index), streamed coalesced from bin[] — no
// candidate list. f64 distance (R4's exact formula -> selection set
// bit-identical to the passing R4/R8/R9). Keep the 32 smallest hit indices
// (binary-search kth when cnt>32), compute h = w1*rel, store h + BN partials.
// 1024 threads = 16 waves = 16 queries per block; no barriers in query work.
// ---------------------------------------------------------------------------
__global__ __launch_bounds__(1024) void k2_query(
    const float* __restrict__ pos, const float* __restrict__ w1,
    const float* __restrict__ radius, float* __restrict__ ws)
{
    __shared__ int   hitl[QBK2][CAP_HIT];    // 8 KB
    __shared__ int   seli[QBK2][KNB];        // 2 KB
    __shared__ float sred[QBK2][6];

    const int tid = threadIdx.x, lane = tid & 63, wave = tid >> 6;
    const int qbase = blockIdx.x * QBK2;
    const int batch = qbase / NPTS;          // QBK2 | NPTS
    const float* bpos = pos + (size_t)batch * NPTS * 3;
    const double rd  = (double)radius[0];
    const double r2d = rd * rd;
    const int G = grid_from_r(rd);
    const float Gf = (float)G;
    const int* cs = (const int*)ws + WS_CS + batch * CSTR;
    const float4* bin = (const float4*)(ws + WS_BIN) + (size_t)batch * NPTS;

    const int qg = qbase + wave;
    const int ql = qg - batch * NPTS;
    const float qx = bpos[ql * 3], qy = bpos[ql * 3 + 1], qz = bpos[ql * 3 + 2];
    const double qxd = (double)qx, qyd = (double)qy, qzd = (double)qz;
    const double qsd = fma(qzd, qzd, fma(qyd, qyd, qxd * qxd));
    const int cx = min((int)(qx * Gf), G - 1);
    const int cy = min((int)(qy * Gf), G - 1);
    const int cz = min((int)(qz * Gf), G - 1);
    const int cx0 = max(cx - 1, 0), cx1 = min(cx + 1, G - 1);

    int hc = 0;
#pragma unroll
    for (int r = 0; r < 9; ++r) {
        const int ny = cy + (r % 3) - 1;
        const int nz = cz + (r / 3) - 1;
        if (ny < 0 || ny >= G || nz < 0 || nz >= G) continue;  // wave-uniform
        const int cb = (nz * G + ny) * G;
        const int s0 = cs[cb + cx0];
        const int s1 = cs[cb + cx1 + 1];
        for (int b0 = s0; b0 < s1; b0 += 64) {
            const int ss = b0 + lane;
            const bool act = ss < s1;
            float4 P = bin[act ? ss : s0];
            double xj = (double)P.x, yj = (double)P.y, zj = (double)P.z;
            double sqj = fma(zj, zj, fma(yj, yj, xj * xj));
            double dot = fma(zj, qzd, fma(yj, qyd, xj * qxd));
            double dd  = (qsd + sqj) - 2.0 * dot;       // exact R4 formula
            bool in = act && (dd < r2d);
            unsigned long long bal = __ballot(in);
            if (in) {
                int p2 = hc + mbcnt64(bal);
                if (p2 < CAP_HIT) hitl[wave][p2] = __float_as_int(P.w);
            }
            hc += (int)__popcll(bal);
        }
    }
    if (hc > CAP_HIT) hc = CAP_HIT;

    // ---- select the 32 smallest hit indices (set only, no order) ----
    if (hc <= KNB) {
        int v = (lane < hc) ? hitl[wave][lane] : 0x7FFFFFFF;
        int mn = v;
#pragma unroll
        for (int off = 32; off; off >>= 1) mn = min(mn, __shfl_xor(mn, off));
        if (lane < KNB) seli[wave][lane] = (lane < hc) ? v : mn;  // pad = min idx
    } else {
        int a = (lane < hc) ? hitl[wave][lane] : 0x7FFFFFFF;
        int b = (64 + lane < hc) ? hitl[wave][64 + lane] : 0x7FFFFFFF;
        int lo = 0, hi = NPTS - 1;       // 32nd smallest (indices distinct)
        while (lo < hi) {
            int mid = (lo + hi) >> 1;
            int c1 = (int)__popcll(__ballot(a <= mid)) +
                     (int)__popcll(__ballot(b <= mid));
            if (c1 >= KNB) hi = mid; else lo = mid + 1;
        }
        const int t = lo;
        unsigned long long ba = __ballot(a <= t);
        unsigned long long bb = __ballot(b <= t);
        int na = (int)__popcll(ba);
        if (a <= t) seli[wave][mbcnt64(ba)] = a;
        if (b <= t) seli[wave][na + mbcnt64(bb)] = b;
    }

    // ---- h epilogue ----
    float w1r[9];
#pragma unroll
    for (int i = 0; i < 9; ++i) w1r[i] = w1[i];

    float ls0 = 0.f, ls1 = 0.f, ls2 = 0.f;
    float lq0 = 0.f, lq1 = 0.f, lq2 = 0.f;
    if (lane < KNB) {
        int j = seli[wave][lane];
        const float* pj = bpos + (size_t)j * 3;
        float rx = __fsub_rn(pj[0], qx);
        float ry = __fsub_rn(pj[1], qy);
        float rz = __fsub_rn(pj[2], qz);
        float h0 = fmaf(rz, w1r[2], fmaf(ry, w1r[1], __fmul_rn(rx, w1r[0])));
        float h1 = fmaf(rz, w1r[5], fmaf(ry, w1r[4], __fmul_rn(rx, w1r[3])));
        float h2 = fmaf(rz, w1r[8], fmaf(ry, w1r[7], __fmul_rn(rx, w1r[6])));
        float* hout = ws + WS_H + (size_t)qg * 3 * KNB;
        hout[0 * KNB + lane] = h0;
        hout[1 * KNB + lane] = h1;
        hout[2 * KNB + lane] = h2;
        ls0 = h0; ls1 = h1; ls2 = h2;
        lq0 = h0 * h0; lq1 = h1 * h1; lq2 = h2 * h2;
    }

    // wave reduce then block reduce of BN partials
#pragma unroll
    for (int m = 1; m < 64; m <<= 1) {
        ls0 += __shfl_xor(ls0, m); ls1 += __shfl_xor(ls1, m); ls2 += __shfl_xor(ls2, m);
        lq0 += __shfl_xor(lq0, m); lq1 += __shfl_xor(lq1, m); lq2 += __shfl_xor(lq2, m);
    }
    if (lane == 0) {
        sred[wave][0] = ls0; sred[wave][1] = ls1; sred[wave][2] = ls2;
        sred[wave][3] = lq0; sred[wave][4] = lq1; sred[wave][5] = lq2;
    }
    __syncthreads();
    if (tid < 6) {
        float s = 0.f;
#pragma unroll
        for (int w = 0; w < QBK2; ++w) s += sred[w][tid];
        ws[WS_PART + tid * NBLK2 + blockIdx.x] = s;
    }
}

// ---------------------------------------------------------------------------
// k3 (fused stats + MLP): block-redundant reduction of 6*NBLK2 partials ->
// mean/inv; then g = relu(((h-mean)*inv)*gamma + beta);
// pe = max_k(g.w2[e] + b2[e]); out = x + pe.
// ---------------------------------------------------------------------------
__global__ __launch_bounds__(256) void k3_mlp(
    const float* __restrict__ ws, const float* __restrict__ gamma,
    const float* __restrict__ beta, const float* __restrict__ w2,
    const float* __restrict__ b2, const float* __restrict__ x,
    float* __restrict__ out)
{
    __shared__ float wred[4][6];
    __shared__ float sstat[6];
    __shared__ float g[4][KNB][3];

    const int tid = threadIdx.x, lane = tid & 63, wave = tid >> 6;

#pragma unroll
    for (int c = 0; c < 6; ++c) {
        float s = 0.f;
        for (int i = tid; i < NBLK2; i += 256) s += ws[WS_PART + c * NBLK2 + i];
#pragma unroll
        for (int m = 1; m < 64; m <<= 1) s += __shfl_xor(s, m);
        if (lane == 0) wred[wave][c] = s;
    }
    __syncthreads();
    if (tid < 3) {
        const double N = (double)((long long)NQ * KNB);
        double s = 0.0, sq = 0.0;
#pragma unroll
        for (int w = 0; w < 4; ++w) { s += wred[w][tid]; sq += wred[w][3 + tid]; }
        double mean = s / N;
        double var  = sq / N - mean * mean;
        sstat[tid]     = (float)mean;
        sstat[3 + tid] = (float)(1.0 / sqrt(var + (double)BN_EPS));
    }
    __syncthreads();

    const float m0 = sstat[0], m1 = sstat[1], m2 = sstat[2];
    const float i0 = sstat[3], i1 = sstat[4], i2 = sstat[5];
    const float g0c = gamma[0], g1c = gamma[1], g2c = gamma[2];
    const float b0c = beta[0],  b1c = beta[1],  b2c = beta[2];
    const float w20 = w2[lane * 3 + 0];
    const float w21 = w2[lane * 3 + 1];
    const float w22 = w2[lane * 3 + 2];
    const float bias = b2[lane];

    const int qg0 = blockIdx.x * QBK2 + wave * 4;
#pragma unroll
    for (int q = 0; q < 4; ++q) {
        const int qg = qg0 + q;
        if (lane < KNB) {
            const float* hin = ws + WS_H + (size_t)qg * 3 * KNB;
            float h0 = hin[0 * KNB + lane];
            float h1 = hin[1 * KNB + lane];
            float h2 = hin[2 * KNB + lane];
            float n0 = __fadd_rn(__fmul_rn(__fmul_rn(__fsub_rn(h0, m0), i0), g0c), b0c);
            float n1 = __fadd_rn(__fmul_rn(__fmul_rn(__fsub_rn(h1, m1), i1), g1c), b1c);
            float n2 = __fadd_rn(__fmul_rn(__fmul_rn(__fsub_rn(h2, m2), i2), g2c), b2c);
            g[wave][lane][0] = fmaxf(n0, 0.0f);
            g[wave][lane][1] = fmaxf(n1, 0.0f);
            g[wave][lane][2] = fmaxf(n2, 0.0f);
        }
        __syncthreads();
        float m = -INFINITY;
#pragma unroll 4
        for (int kk = 0; kk < KNB; ++kk) {
            float ga = g[wave][kk][0], gb = g[wave][kk][1], gc = g[wave][kk][2];
            float pe = __fadd_rn(fmaf(gc, w22, fmaf(gb, w21, __fmul_rn(ga, w20))), bias);
            m = fmaxf(m, pe);
        }
        const size_t o = (size_t)qg * CFEAT + lane;
        out[o] = __fadd_rn(x[o], m);
        __syncthreads();
    }
}

// ---------------------------------------------------------------------------
extern "C" void kernel_launch(void* const* d_in, const int* in_sizes, int n_in,
                              void* d_out, int out_size, void* d_ws, size_t ws_size,
                              hipStream_t stream) {
    (void)in_sizes; (void)n_in; (void)out_size; (void)ws_size;
    const float* pos    = (const float*)d_in[0];
    const float* x      = (const float*)d_in[1];
    const float* w1     = (const float*)d_in[2];
    const float* gamma  = (const float*)d_in[3];
    const float* beta   = (const float*)d_in[4];
    const float* w2     = (const float*)d_in[5];
    const float* b2     = (const float*)d_in[6];
    const float* radius = (const float*)d_in[7];
    // d_in[8] = k, fixed at 32 (compile-time KNB)
    float* out = (float*)d_out;
    float* ws  = (float*)d_ws;

    hipLaunchKernelGGL(kA_bin,   dim3(NBATCH), dim3(1024), 0, stream, pos, radius, ws);
    hipLaunchKernelGGL(k2_query, dim3(NBLK2),  dim3(1024), 0, stream, pos, w1, radius, ws);
    hipLaunchKernelGGL(k3_mlp,   dim3(NBLK2),  dim3(256),  0, stream,
                       ws, gamma, beta, w2, b2, x, out);
}